// Round 9
// baseline (185.076 us; speedup 1.0000x reference)
//
#include <hip/hip_runtime.h>
#include <cstdint>
#include <cstddef>

typedef __attribute__((ext_vector_type(8))) __bf16 bf16x8;
typedef __attribute__((ext_vector_type(4))) float f32x4;
typedef __attribute__((ext_vector_type(8))) unsigned short u16x8;

__device__ __forceinline__ unsigned short f2bf(float f) {
  union { float f; unsigned u; } v; v.f = f;
  unsigned u = v.u;
  return (unsigned short)((u + 0x7FFFu + ((u >> 16) & 1u)) >> 16);
}

__device__ __forceinline__ unsigned cvtpk(float lo, float hi) {
  unsigned r;
  asm("v_cvt_pk_bf16_f32 %0, %1, %2" : "=v"(r) : "v"(lo), "v"(hi));
  return r;
}

__device__ __forceinline__ void async16(const void* g, void* l) {
  __builtin_amdgcn_global_load_lds(
      (const __attribute__((address_space(1))) unsigned int*)g,
      (__attribute__((address_space(3))) unsigned int*)l, 16, 0, 0);
}

// ---------------- prologue: W expand -> M stored [N][K] bf16 ----------------
__global__ __launch_bounds__(256) void prep_kern(const float* __restrict__ W,
                                                 unsigned short* __restrict__ Mb) {
  int pair = blockIdx.x * 4 + (threadIdx.x >> 6);  // (i,j) flat index
  int sub = threadIdx.x >> 6, c = threadIdx.x & 63;
  int i = pair >> 6, j = pair & 63;
  __shared__ unsigned short w16[4][64];
  w16[sub][c] = f2bf(W[(size_t)pair * 64 + c]);
  __syncthreads();
  unsigned short* dst = Mb + (size_t)(i * 64 + c) * 4096 + j * 64;
#pragma unroll
  for (int g = 0; g < 8; ++g) {
    u16x8 v;
#pragma unroll
    for (int e = 0; e < 8; ++e) v[e] = w16[sub][(c - (g * 8 + e)) & 63];
    *(u16x8*)(dst + g * 8) = v;
  }
}

// ---------------- main GEMM: 256x256, BK=64, 16x16x32, 3-barrier tile ----------------
// A read DIRECTLY from fp32 x: per tile, S0 issues 8 global_load_dwordx4 of
// tile t+1's A-rows (tile-local regs); S2 does vmcnt -> cvt_pk_bf16 -> 4
// ds_write_b128 into buf[nxt]'s A region (dead since t-1's b2). B stays on the
// global_load_lds path, staged t+2 ahead. vmcnt ledger: enter tile with
// B(t+1)x4 outstanding; S0 +8, S1 +4 -> vmcnt(4) retires A(t+1)+B(t+1).
#define FE asm volatile("" ::: "memory")
#define BARRIER() do { FE; __builtin_amdgcn_s_barrier(); FE; } while (0)

#define MFQ(AF, MB, BF, NB)                                                      \
  __builtin_amdgcn_s_setprio(1);                                                 \
  _Pragma("unroll") for (int ks = 0; ks < 2; ++ks)                               \
      _Pragma("unroll") for (int mi = 0; mi < 4; ++mi)                           \
      _Pragma("unroll") for (int ni = 0; ni < 2; ++ni)                           \
      acc[(MB) + mi][(NB) + ni] = __builtin_amdgcn_mfma_f32_16x16x32_bf16(       \
          AF[mi][ks], BF[ni][ks], acc[(MB) + mi][(NB) + ni], 0, 0, 0);           \
  __builtin_amdgcn_s_setprio(0);

// MODE: 0 steady, 1 = tt==62 (A(63) only, vmcnt(0)), 2 = tt==63 (final, bare)
#define TILE_BODY(TT, CUR, MODE)                                                 \
  do {                                                                           \
    const char* pa = lds + (CUR) * 65536 + wm * 128;                             \
    const char* pb = lds + (CUR) * 65536 + 32768 + wn * 128;                     \
    bf16x8 a0[4][2], a1[4][2], bl[2][2], bh[2][2];                               \
    float4 xr[8];                                                                \
    /* ---- S0: issue A(t+1) fp32 loads; read aL+bL+bH; MFMA (0,0),(0,1) ---- */ \
    if ((MODE) < 2) {                                                            \
      _Pragma("unroll") for (int h = 0; h < 2; ++h)                              \
          _Pragma("unroll") for (int i = 0; i < 2; ++i) {                        \
        const float4* sp = Xf4 +                                                 \
            (size_t)(xrow0 + h * 128 + i * 64) * 1024 + ((TT) + 1) * 16 + cslot * 2; \
        xr[(h * 2 + i) * 2] = sp[0];                                             \
        xr[(h * 2 + i) * 2 + 1] = sp[1];                                         \
      }                                                                          \
    }                                                                            \
    _Pragma("unroll") for (int mi = 0; mi < 4; ++mi)                             \
        _Pragma("unroll") for (int ks = 0; ks < 2; ++ks)                         \
        a0[mi][ks] = *(const bf16x8*)(pa + koff[ks] + mi * 2048);                \
    _Pragma("unroll") for (int ni = 0; ni < 2; ++ni)                             \
        _Pragma("unroll") for (int ks = 0; ks < 2; ++ks)                         \
        bl[ni][ks] = *(const bf16x8*)(pb + koff[ks] + ni * 2048);                \
    _Pragma("unroll") for (int ni = 0; ni < 2; ++ni)                             \
        _Pragma("unroll") for (int ks = 0; ks < 2; ++ks)                         \
        bh[ni][ks] = *(const bf16x8*)(pb + koff[ks] + (2 + ni) * 2048);          \
    MFQ(a0, 0, bl, 0)                                                            \
    MFQ(a0, 0, bh, 2)                                                            \
    BARRIER(); /* b1: B region of buf[cur] consumed */                           \
    /* ---- S1: read aH; async16 B(t+2); MFMA (1,1) ---- */                      \
    _Pragma("unroll") for (int mi = 0; mi < 4; ++mi)                             \
        _Pragma("unroll") for (int ks = 0; ks < 2; ++ks)                         \
        a1[mi][ks] = *(const bf16x8*)(pa + koff[ks] + (4 + mi) * 2048);          \
    if ((MODE) == 0) {                                                           \
      stageB((TT) + 2, 0);                                                       \
      stageB((TT) + 2, 1);                                                       \
    }                                                                            \
    MFQ(a1, 4, bh, 2)                                                            \
    BARRIER(); /* b2: A region of buf[cur] consumed */                           \
    /* ---- S2: vmcnt; cvt+ds_write A(t+1) into buf[nxt]; MFMA (1,0) ---- */     \
    if ((MODE) == 0)                                                             \
      asm volatile("s_waitcnt vmcnt(4)" ::: "memory");                           \
    else if ((MODE) == 1)                                                        \
      asm volatile("s_waitcnt vmcnt(0)" ::: "memory");                           \
    if ((MODE) < 2) {                                                            \
      char* wd = lds + ((CUR) ^ 1) * 65536 + w * 1024 + l * 16;                  \
      _Pragma("unroll") for (int h = 0; h < 2; ++h)                              \
          _Pragma("unroll") for (int i = 0; i < 2; ++i) {                        \
        float4 u0 = xr[(h * 2 + i) * 2], u1 = xr[(h * 2 + i) * 2 + 1];           \
        uint4 pk;                                                                \
        pk.x = cvtpk(u0.x, u0.y); pk.y = cvtpk(u0.z, u0.w);                      \
        pk.z = cvtpk(u1.x, u1.y); pk.w = cvtpk(u1.z, u1.w);                      \
        *(uint4*)(wd + h * 16384 + i * 8192) = pk;                               \
      }                                                                          \
    }                                                                            \
    MFQ(a1, 4, bl, 0)                                                            \
    if ((MODE) < 2) {                                                            \
      asm volatile("s_waitcnt lgkmcnt(0)" ::: "memory");                         \
      BARRIER(); /* b3: buffer swap */                                           \
    }                                                                            \
  } while (0)

__global__ __launch_bounds__(512, 2) void gemm8(const float* __restrict__ X,
                                                const unsigned short* __restrict__ B,
                                                float* __restrict__ C) {
  __shared__ __align__(16) char lds[131072];
  int bid = blockIdx.x;
  int swz = (bid & 7) * 32 + (bid >> 3);  // bijective: 256 = 8*32
  int bm = swz >> 4, bn = swz & 15;
  int t = threadIdx.x;
  int w = t >> 6, l = t & 63;
  int wm = (w >> 2) * 128;  // 2 M-groups
  int wn = (w & 3) * 64;    // 4 N-groups

  f32x4 acc[8][4];
#pragma unroll
  for (int a_ = 0; a_ < 8; ++a_)
#pragma unroll
    for (int b_ = 0; b_ < 4; ++b_) acc[a_][b_] = (f32x4){0.f, 0.f, 0.f, 0.f};

  const int rowin = w * 8 + (l >> 3);    // staging row within 64-row group
  const int cslot = (l & 7) ^ (l >> 3);  // pre-swizzled global k-slot
  const float4* Xf4 = (const float4*)X;
  const int xrow0 = bm * 256 + rowin;
  int koff[2];
#pragma unroll
  for (int ks = 0; ks < 2; ++ks)
    koff[ks] = (l & 15) * 128 + ((ks * 4 + (l >> 4)) ^ (l & 7)) * 16;

  const size_t bbase = (size_t)bn * 256 * 4096;

  auto stageB = [&](int kt, int half) {
    char* ldst = lds + (kt & 1) * 65536 + 32768 + half * 16384 + w * 1024;
#pragma unroll
    for (int i = 0; i < 2; ++i) {
      int r = half * 128 + i * 64 + rowin;
      async16(B + bbase + (size_t)r * 4096 + kt * 64 + cslot * 8, ldst + i * 8192);
    }
  };

  // prologue: B(0), B(1) via async16; A(0) via reg-load + cvt + ds_write
  stageB(0, 0); stageB(0, 1);
  stageB(1, 0); stageB(1, 1);
  {
    float4 xr[8];
#pragma unroll
    for (int h = 0; h < 2; ++h)
#pragma unroll
      for (int i = 0; i < 2; ++i) {
        const float4* sp = Xf4 + (size_t)(xrow0 + h * 128 + i * 64) * 1024 + cslot * 2;
        xr[(h * 2 + i) * 2] = sp[0];
        xr[(h * 2 + i) * 2 + 1] = sp[1];
      }
    asm volatile("s_waitcnt vmcnt(0)" ::: "memory");
    char* wd = lds + w * 1024 + l * 16;
#pragma unroll
    for (int h = 0; h < 2; ++h)
#pragma unroll
      for (int i = 0; i < 2; ++i) {
        float4 u0 = xr[(h * 2 + i) * 2], u1 = xr[(h * 2 + i) * 2 + 1];
        uint4 pk;
        pk.x = cvtpk(u0.x, u0.y); pk.y = cvtpk(u0.z, u0.w);
        pk.z = cvtpk(u1.x, u1.y); pk.w = cvtpk(u1.z, u1.w);
        *(uint4*)(wd + h * 16384 + i * 8192) = pk;
      }
    asm volatile("s_waitcnt lgkmcnt(0)" ::: "memory");
  }
  BARRIER();

  for (int tt = 0; tt < 62; tt += 2) {
    TILE_BODY(tt, 0, 0);
    TILE_BODY(tt + 1, 1, 0);
  }
  TILE_BODY(62, 0, 1);
  TILE_BODY(63, 1, 2);

#undef TILE_BODY
#undef MFQ

  // C/D layout (m89-verified): col = lane&15, row = (lane>>4)*4 + reg
  int r0 = (l >> 4) * 4;
#pragma unroll
  for (int mi = 0; mi < 8; ++mi) {
    size_t row = (size_t)(bm * 256 + wm + mi * 16 + r0);
#pragma unroll
    for (int ni = 0; ni < 4; ++ni) {
      int col = bn * 256 + wn + ni * 16 + (l & 15);
#pragma unroll
      for (int r = 0; r < 4; ++r)
        C[(row + r) * 4096 + col] = acc[mi][ni][r];
    }
  }
}

// ---------------- fallback (no workspace): fp32 register-blocked ----------------
__global__ __launch_bounds__(256) void fallback_kern(const float* __restrict__ x,
                                                     const float* __restrict__ W,
                                                     float* __restrict__ out) {
  int bi = blockIdx.x & 63;
  int bb = blockIdx.x >> 6;
  int t = threadIdx.x;
  int m = t & 63;
  int cg = t >> 6;
  __shared__ float xs[64][65];
  __shared__ float ws[64];
  float acc[16];
#pragma unroll
  for (int e = 0; e < 16; ++e) acc[e] = 0.f;
  for (int j = 0; j < 64; ++j) {
    __syncthreads();
#pragma unroll
    for (int r = 0; r < 16; ++r) {
      int idx = t + 256 * r;
      int rr = idx >> 6, cc = idx & 63;
      xs[rr][cc] = x[(size_t)(bb * 64 + rr) * 4096 + j * 64 + cc];
    }
    if (t < 64) ws[t] = W[((size_t)(bi * 64 + j)) * 64 + t];
    __syncthreads();
    float xr[64];
#pragma unroll
    for (int e = 0; e < 64; ++e) xr[e] = xs[m][(cg * 16 + e) & 63];
#pragma unroll
    for (int mm = 0; mm < 64; ++mm) {
      float wv = ws[mm];
#pragma unroll
      for (int cc2 = 0; cc2 < 16; ++cc2)
        acc[cc2] = __builtin_fmaf(xr[(cc2 - mm) & 63], wv, acc[cc2]);
    }
  }
  float* dst = out + (size_t)(bb * 64 + m) * 4096 + bi * 64 + cg * 16;
#pragma unroll
  for (int cc2 = 0; cc2 < 16; ++cc2) dst[cc2] = acc[cc2];
}

extern "C" void kernel_launch(void* const* d_in, const int* in_sizes, int n_in,
                              void* d_out, int out_size, void* d_ws, size_t ws_size,
                              hipStream_t stream) {
  const float* x = (const float*)d_in[0];
  const float* W = (const float*)d_in[1];
  float* out = (float*)d_out;
  const size_t need = (size_t)4096 * 4096 * sizeof(unsigned short);  // 32 MB
  if (ws_size >= need) {
    unsigned short* Mb = (unsigned short*)d_ws;
    prep_kern<<<dim3(1024), dim3(256), 0, stream>>>(W, Mb);
    gemm8<<<dim3(256), dim3(512), 0, stream>>>(x, Mb, out);
  } else {
    fallback_kern<<<dim3(4096), dim3(256), 0, stream>>>(x, W, out);
  }
}

// Round 10
// 141.656 us; speedup vs baseline: 1.3065x; 1.3065x over previous
//
#include <hip/hip_runtime.h>
#include <cstdint>
#include <cstddef>

typedef __attribute__((ext_vector_type(8))) __bf16 bf16x8;
typedef __attribute__((ext_vector_type(4))) float f32x4;
typedef __attribute__((ext_vector_type(8))) unsigned short u16x8;

__device__ __forceinline__ unsigned short f2bf(float f) {
  union { float f; unsigned u; } v; v.f = f;
  unsigned u = v.u;
  return (unsigned short)((u + 0x7FFFu + ((u >> 16) & 1u)) >> 16);
}

__device__ __forceinline__ void async16(const void* g, void* l) {
  __builtin_amdgcn_global_load_lds(
      (const __attribute__((address_space(1))) unsigned int*)g,
      (__attribute__((address_space(3))) unsigned int*)l, 16, 0, 0);
}

// ---------------- fused prologue: x fp32->bf16 (blocks 0..8191) +
//                  W expand -> M stored [N][K] bf16 (blocks 8192..9215) ----------------
__global__ __launch_bounds__(256) void prep_kern(const float* __restrict__ x,
                                                 const float* __restrict__ W,
                                                 unsigned short* __restrict__ xb,
                                                 unsigned short* __restrict__ Mb) {
  int b = blockIdx.x;
  if (b < 8192) {
    int idx = b * 256 + threadIdx.x;
    const float4* src = (const float4*)x + (size_t)idx * 2;
    float4 a = src[0], b4 = src[1];
    u16x8 v;
    v[0] = f2bf(a.x); v[1] = f2bf(a.y); v[2] = f2bf(a.z); v[3] = f2bf(a.w);
    v[4] = f2bf(b4.x); v[5] = f2bf(b4.y); v[6] = f2bf(b4.z); v[7] = f2bf(b4.w);
    *((u16x8*)xb + idx) = v;
  } else {
    int pair = (b - 8192) * 4 + (threadIdx.x >> 6);  // (i,j) flat index
    int sub = threadIdx.x >> 6, c = threadIdx.x & 63;
    int i = pair >> 6, j = pair & 63;
    __shared__ unsigned short w16[4][64];
    w16[sub][c] = f2bf(W[(size_t)pair * 64 + c]);
    __syncthreads();
    unsigned short* dst = Mb + (size_t)(i * 64 + c) * 4096 + j * 64;
#pragma unroll
    for (int g = 0; g < 8; ++g) {
      u16x8 v;
#pragma unroll
      for (int e = 0; e < 8; ++e) v[e] = w16[sub][(c - (g * 8 + e)) & 63];
      *(u16x8*)(dst + g * 8) = v;
    }
  }
}

// ---------------- main GEMM: 256x256, BK=64, 16x16x32, 2-barrier tile ----------------
// r8 data path (slot^(row&7) involution, deep t+2 prefetch, tile-local frags),
// barriers cut 3 -> 2 per K-tile:
//   S0: read a0,bl,bh; MFQ(0,0); MFQ(0,1) [a0 dies]; read a1; MFQ(1,1)
//   b1: ALL reads of buf[cur] retired (reg-resident before each wave's MFMAs)
//       -> both A and B regions of buf[cur] free
//   S1: stage tile t+2 (8 async16 into buf[cur]); MFQ(1,0) reg-only;
//       vmcnt(8) retires tile t+1's stages; b2: buffer swap
#define FE asm volatile("" ::: "memory")
#define BARRIER() do { FE; __builtin_amdgcn_s_barrier(); FE; } while (0)

#define MFQ(AF, MB, BF, NB)                                                      \
  __builtin_amdgcn_s_setprio(1);                                                 \
  _Pragma("unroll") for (int ks = 0; ks < 2; ++ks)                               \
      _Pragma("unroll") for (int mi = 0; mi < 4; ++mi)                           \
      _Pragma("unroll") for (int ni = 0; ni < 2; ++ni)                           \
      acc[(MB) + mi][(NB) + ni] = __builtin_amdgcn_mfma_f32_16x16x32_bf16(       \
          AF[mi][ks], BF[ni][ks], acc[(MB) + mi][(NB) + ni], 0, 0, 0);           \
  __builtin_amdgcn_s_setprio(0);

// MODE: 0 steady, 1 = tt==62 (no stages, vmcnt(0)), 2 = tt==63 (final, bare)
#define TILE_BODY(TT, CUR, MODE)                                                 \
  do {                                                                           \
    const char* pa = lds + (CUR) * 65536 + wm * 128;                             \
    const char* pb = lds + (CUR) * 65536 + 32768 + wn * 128;                     \
    bf16x8 a0[4][2], a1[4][2], bl[2][2], bh[2][2];                               \
    /* ---- S0: all fragment reads + 3 MFMA quads ---- */                        \
    _Pragma("unroll") for (int mi = 0; mi < 4; ++mi)                             \
        _Pragma("unroll") for (int ks = 0; ks < 2; ++ks)                         \
        a0[mi][ks] = *(const bf16x8*)(pa + koff[ks] + mi * 2048);                \
    _Pragma("unroll") for (int ni = 0; ni < 2; ++ni)                             \
        _Pragma("unroll") for (int ks = 0; ks < 2; ++ks)                         \
        bl[ni][ks] = *(const bf16x8*)(pb + koff[ks] + ni * 2048);                \
    _Pragma("unroll") for (int ni = 0; ni < 2; ++ni)                             \
        _Pragma("unroll") for (int ks = 0; ks < 2; ++ks)                         \
        bh[ni][ks] = *(const bf16x8*)(pb + koff[ks] + (2 + ni) * 2048);          \
    MFQ(a0, 0, bl, 0)                                                            \
    MFQ(a0, 0, bh, 2)                                                            \
    _Pragma("unroll") for (int mi = 0; mi < 4; ++mi)                             \
        _Pragma("unroll") for (int ks = 0; ks < 2; ++ks)                         \
        a1[mi][ks] = *(const bf16x8*)(pa + koff[ks] + (4 + mi) * 2048);          \
    MFQ(a1, 4, bh, 2)                                                            \
    BARRIER(); /* b1: buf[cur] fully consumed (A and B regions) */               \
    /* ---- S1: stage t+2 (both A and B); MFQ(1,0); vmcnt; swap ---- */          \
    if ((MODE) == 0) {                                                           \
      stage((TT) + 2, 2);                                                        \
      stage((TT) + 2, 3);                                                        \
      stage((TT) + 2, 0);                                                        \
      stage((TT) + 2, 1);                                                        \
    }                                                                            \
    MFQ(a1, 4, bl, 0)                                                            \
    if ((MODE) == 0)                                                             \
      asm volatile("s_waitcnt vmcnt(8)" ::: "memory");                           \
    else if ((MODE) == 1)                                                        \
      asm volatile("s_waitcnt vmcnt(0)" ::: "memory");                           \
    if ((MODE) < 2) BARRIER(); /* b2: buffer swap */                             \
  } while (0)

__global__ __launch_bounds__(512, 2) void gemm8(const unsigned short* __restrict__ A,
                                                const unsigned short* __restrict__ B,
                                                float* __restrict__ C) {
  __shared__ __align__(16) char lds[131072];
  int bid = blockIdx.x;
  int swz = (bid & 7) * 32 + (bid >> 3);  // bijective: 256 = 8*32
  int bm = swz >> 4, bn = swz & 15;
  int t = threadIdx.x;
  int w = t >> 6, l = t & 63;
  int wm = (w >> 2) * 128;  // 2 M-groups
  int wn = (w & 3) * 64;    // 4 N-groups

  f32x4 acc[8][4];
#pragma unroll
  for (int a_ = 0; a_ < 8; ++a_)
#pragma unroll
    for (int b_ = 0; b_ < 4; ++b_) acc[a_][b_] = (f32x4){0.f, 0.f, 0.f, 0.f};

  const int rowin = w * 8 + (l >> 3);    // staging row within 64-row group
  const int cslot = (l & 7) ^ (l >> 3);  // pre-swizzled global k-slot
  int koff[2];
#pragma unroll
  for (int ks = 0; ks < 2; ++ks)
    koff[ks] = (l & 15) * 128 + ((ks * 4 + (l >> 4)) ^ (l & 7)) * 16;

  const size_t abase = (size_t)bm * 256 * 4096;
  const size_t bbase = (size_t)bn * 256 * 4096;

  auto stage = [&](int kt, int c) {
    const unsigned short* mat = (c < 2) ? A : B;
    size_t gbase = (c < 2) ? abase : bbase;
    int half = c & 1;
    char* ldst = lds + (kt & 1) * 65536 + ((c < 2) ? 0 : 32768) + half * 16384 + w * 1024;
#pragma unroll
    for (int i = 0; i < 2; ++i) {
      int r = half * 128 + i * 64 + rowin;
      async16(mat + gbase + (size_t)r * 4096 + kt * 64 + cslot * 8, ldst + i * 8192);
    }
  };

  // prologue: tiles 0 and 1 fully staged (8 + 8 loads); tile 0 landed
#pragma unroll
  for (int c = 0; c < 4; ++c) stage(0, c);
#pragma unroll
  for (int c = 0; c < 4; ++c) stage(1, c);
  asm volatile("s_waitcnt vmcnt(8)" ::: "memory");
  BARRIER();

  for (int tt = 0; tt < 62; tt += 2) {
    TILE_BODY(tt, 0, 0);
    TILE_BODY(tt + 1, 1, 0);
  }
  TILE_BODY(62, 0, 1);
  TILE_BODY(63, 1, 2);

#undef TILE_BODY
#undef MFQ

  // C/D layout (m89-verified): col = lane&15, row = (lane>>4)*4 + reg
  int r0 = (l >> 4) * 4;
#pragma unroll
  for (int mi = 0; mi < 8; ++mi) {
    size_t row = (size_t)(bm * 256 + wm + mi * 16 + r0);
#pragma unroll
    for (int ni = 0; ni < 4; ++ni) {
      int col = bn * 256 + wn + ni * 16 + (l & 15);
#pragma unroll
      for (int r = 0; r < 4; ++r)
        C[(row + r) * 4096 + col] = acc[mi][ni][r];
    }
  }
}

// ---------------- fallback (no workspace): fp32 register-blocked ----------------
__global__ __launch_bounds__(256) void fallback_kern(const float* __restrict__ x,
                                                     const float* __restrict__ W,
                                                     float* __restrict__ out) {
  int bi = blockIdx.x & 63;
  int bb = blockIdx.x >> 6;
  int t = threadIdx.x;
  int m = t & 63;
  int cg = t >> 6;
  __shared__ float xs[64][65];
  __shared__ float ws[64];
  float acc[16];
#pragma unroll
  for (int e = 0; e < 16; ++e) acc[e] = 0.f;
  for (int j = 0; j < 64; ++j) {
    __syncthreads();
#pragma unroll
    for (int r = 0; r < 16; ++r) {
      int idx = t + 256 * r;
      int rr = idx >> 6, cc = idx & 63;
      xs[rr][cc] = x[(size_t)(bb * 64 + rr) * 4096 + j * 64 + cc];
    }
    if (t < 64) ws[t] = W[((size_t)(bi * 64 + j)) * 64 + t];
    __syncthreads();
    float xr[64];
#pragma unroll
    for (int e = 0; e < 64; ++e) xr[e] = xs[m][(cg * 16 + e) & 63];
#pragma unroll
    for (int mm = 0; mm < 64; ++mm) {
      float wv = ws[mm];
#pragma unroll
      for (int cc2 = 0; cc2 < 16; ++cc2)
        acc[cc2] = __builtin_fmaf(xr[(cc2 - mm) & 63], wv, acc[cc2]);
    }
  }
  float* dst = out + (size_t)(bb * 64 + m) * 4096 + bi * 64 + cg * 16;
#pragma unroll
  for (int cc2 = 0; cc2 < 16; ++cc2) dst[cc2] = acc[cc2];
}

extern "C" void kernel_launch(void* const* d_in, const int* in_sizes, int n_in,
                              void* d_out, int out_size, void* d_ws, size_t ws_size,
                              hipStream_t stream) {
  const float* x = (const float*)d_in[0];
  const float* W = (const float*)d_in[1];
  float* out = (float*)d_out;
  const size_t need = (size_t)2 * 4096 * 4096 * sizeof(unsigned short);  // 64 MB
  if (ws_size >= need) {
    unsigned short* xb = (unsigned short*)d_ws;
    unsigned short* Mb = xb + (size_t)4096 * 4096;
    prep_kern<<<dim3(9216), dim3(256), 0, stream>>>(x, W, xb, Mb);
    gemm8<<<dim3(256), dim3(512), 0, stream>>>(xb, Mb, out);
  } else {
    fallback_kern<<<dim3(4096), dim3(256), 0, stream>>>(x, W, out);
  }
}

// Round 11
// 137.651 us; speedup vs baseline: 1.3445x; 1.0291x over previous
//
#include <hip/hip_runtime.h>
#include <cstdint>
#include <cstddef>

typedef __attribute__((ext_vector_type(8))) __bf16 bf16x8;
typedef __attribute__((ext_vector_type(4))) float f32x4;
typedef __attribute__((ext_vector_type(8))) unsigned short u16x8;

__device__ __forceinline__ unsigned short f2bf(float f) {
  union { float f; unsigned u; } v; v.f = f;
  unsigned u = v.u;
  return (unsigned short)((u + 0x7FFFu + ((u >> 16) & 1u)) >> 16);
}

__device__ __forceinline__ void async16(const void* g, void* l) {
  __builtin_amdgcn_global_load_lds(
      (const __attribute__((address_space(1))) unsigned int*)g,
      (__attribute__((address_space(3))) unsigned int*)l, 16, 0, 0);
}

// ---------------- fused prologue: x fp32->bf16 (blocks 0..8191) +
//                  W expand -> M stored [N][K] bf16 (blocks 8192..9215) ----------------
__global__ __launch_bounds__(256) void prep_kern(const float* __restrict__ x,
                                                 const float* __restrict__ W,
                                                 unsigned short* __restrict__ xb,
                                                 unsigned short* __restrict__ Mb) {
  int b = blockIdx.x;
  if (b < 8192) {
    int idx = b * 256 + threadIdx.x;
    const float4* src = (const float4*)x + (size_t)idx * 2;
    float4 a = src[0], b4 = src[1];
    u16x8 v;
    v[0] = f2bf(a.x); v[1] = f2bf(a.y); v[2] = f2bf(a.z); v[3] = f2bf(a.w);
    v[4] = f2bf(b4.x); v[5] = f2bf(b4.y); v[6] = f2bf(b4.z); v[7] = f2bf(b4.w);
    *((u16x8*)xb + idx) = v;
  } else {
    int pair = (b - 8192) * 4 + (threadIdx.x >> 6);  // (i,j) flat index
    int sub = threadIdx.x >> 6, c = threadIdx.x & 63;
    int i = pair >> 6, j = pair & 63;
    __shared__ unsigned short w16[4][64];
    w16[sub][c] = f2bf(W[(size_t)pair * 64 + c]);
    __syncthreads();
    unsigned short* dst = Mb + (size_t)(i * 64 + c) * 4096 + j * 64;
#pragma unroll
    for (int g = 0; g < 8; ++g) {
      u16x8 v;
#pragma unroll
      for (int e = 0; e < 8; ++e) v[e] = w16[sub][(c - (g * 8 + e)) & 63];
      *(u16x8*)(dst + g * 8) = v;
    }
  }
}

// ---------------- main GEMM: 256x256, BK=64, 16x16x32, 3-barrier tile ----------------
// Empirical optimum (r8): barrier curve 9->129us, 7->124, 3->115, 2->123;
// 16x16x32 beats 32x32x16 here (LDS conflict-free under the slot^(row&7)
// involution); t+2 prefetch with counted vmcnt(8); all fragments tile-local.
//   S0: read aL(8)+bL(4)+bH(4); MFMA (0,0),(0,1)    [reads retired via MFMA lgkm]
//   b1; S1: read aH(8); stage t+2 B; MFMA (1,1)
//   b2; stage t+2 A; MFMA (1,0); vmcnt(8); b3 (boundary)
// b1 guards stage-B WAR, b2 guards stage-A WAR, b3 guards buffer swap RAW.
#define FE asm volatile("" ::: "memory")
#define BARRIER() do { FE; __builtin_amdgcn_s_barrier(); FE; } while (0)

#define MFQ(AF, MB, BF, NB)                                                      \
  __builtin_amdgcn_s_setprio(1);                                                 \
  _Pragma("unroll") for (int ks = 0; ks < 2; ++ks)                               \
      _Pragma("unroll") for (int mi = 0; mi < 4; ++mi)                           \
      _Pragma("unroll") for (int ni = 0; ni < 2; ++ni)                           \
      acc[(MB) + mi][(NB) + ni] = __builtin_amdgcn_mfma_f32_16x16x32_bf16(       \
          AF[mi][ks], BF[ni][ks], acc[(MB) + mi][(NB) + ni], 0, 0, 0);           \
  __builtin_amdgcn_s_setprio(0);

// MODE: 0 steady, 1 = tt==62 (no stages, boundary vmcnt(0)), 2 = tt==63 (final)
#define TILE_BODY(TT, CUR, MODE)                                                 \
  do {                                                                           \
    const char* pa = lds + (CUR) * 65536 + wm * 128;                             \
    const char* pb = lds + (CUR) * 65536 + 32768 + wn * 128;                     \
    bf16x8 a0[4][2], a1[4][2], bl[2][2], bh[2][2];                               \
    /* ---- S0: read aL+bL+bH; MFMA (0,0) and (0,1) ---- */                      \
    _Pragma("unroll") for (int mi = 0; mi < 4; ++mi)                             \
        _Pragma("unroll") for (int ks = 0; ks < 2; ++ks)                         \
        a0[mi][ks] = *(const bf16x8*)(pa + koff[ks] + mi * 2048);                \
    _Pragma("unroll") for (int ni = 0; ni < 2; ++ni)                             \
        _Pragma("unroll") for (int ks = 0; ks < 2; ++ks)                         \
        bl[ni][ks] = *(const bf16x8*)(pb + koff[ks] + ni * 2048);                \
    _Pragma("unroll") for (int ni = 0; ni < 2; ++ni)                             \
        _Pragma("unroll") for (int ks = 0; ks < 2; ++ks)                         \
        bh[ni][ks] = *(const bf16x8*)(pb + koff[ks] + (2 + ni) * 2048);          \
    MFQ(a0, 0, bl, 0)                                                            \
    MFQ(a0, 0, bh, 2)                                                            \
    BARRIER(); /* b1: all waves consumed aL,bL,bH -> B region reusable */        \
    /* ---- S1: read aH; stage t+2 B; MFMA (1,1) ---- */                         \
    _Pragma("unroll") for (int mi = 0; mi < 4; ++mi)                             \
        _Pragma("unroll") for (int ks = 0; ks < 2; ++ks)                         \
        a1[mi][ks] = *(const bf16x8*)(pa + koff[ks] + (4 + mi) * 2048);          \
    if ((MODE) == 0) {                                                           \
      stage((TT) + 2, 2);                                                        \
      stage((TT) + 2, 3);                                                        \
    }                                                                            \
    MFQ(a1, 4, bh, 2)                                                            \
    BARRIER(); /* b2: all waves consumed aH -> A region reusable */              \
    /* ---- S2: stage t+2 A; MFMA (1,0); boundary vmcnt + barrier ---- */        \
    if ((MODE) == 0) {                                                           \
      stage((TT) + 2, 0);                                                        \
      stage((TT) + 2, 1);                                                        \
    }                                                                            \
    MFQ(a1, 4, bl, 0)                                                            \
    if ((MODE) == 0)                                                             \
      asm volatile("s_waitcnt vmcnt(8)" ::: "memory");                           \
    else if ((MODE) == 1)                                                        \
      asm volatile("s_waitcnt vmcnt(0)" ::: "memory");                           \
    if ((MODE) < 2) BARRIER(); /* b3: buffer swap */                             \
  } while (0)

__global__ __launch_bounds__(512, 2) void gemm8(const unsigned short* __restrict__ A,
                                                const unsigned short* __restrict__ B,
                                                float* __restrict__ C) {
  __shared__ __align__(16) char lds[131072];
  int bid = blockIdx.x;
  int swz = (bid & 7) * 32 + (bid >> 3);  // bijective: 256 = 8*32
  int bm = swz >> 4, bn = swz & 15;
  int t = threadIdx.x;
  int w = t >> 6, l = t & 63;
  int wm = (w >> 2) * 128;  // 2 M-groups
  int wn = (w & 3) * 64;    // 4 N-groups

  f32x4 acc[8][4];
#pragma unroll
  for (int a_ = 0; a_ < 8; ++a_)
#pragma unroll
    for (int b_ = 0; b_ < 4; ++b_) acc[a_][b_] = (f32x4){0.f, 0.f, 0.f, 0.f};

  const int rowin = w * 8 + (l >> 3);    // staging row within 64-row group
  const int cslot = (l & 7) ^ (l >> 3);  // pre-swizzled global k-slot
  int koff[2];
#pragma unroll
  for (int ks = 0; ks < 2; ++ks)
    koff[ks] = (l & 15) * 128 + ((ks * 4 + (l >> 4)) ^ (l & 7)) * 16;

  const size_t abase = (size_t)bm * 256 * 4096;
  const size_t bbase = (size_t)bn * 256 * 4096;

  auto stage = [&](int kt, int c) {
    const unsigned short* mat = (c < 2) ? A : B;
    size_t gbase = (c < 2) ? abase : bbase;
    int half = c & 1;
    char* ldst = lds + (kt & 1) * 65536 + ((c < 2) ? 0 : 32768) + half * 16384 + w * 1024;
#pragma unroll
    for (int i = 0; i < 2; ++i) {
      int r = half * 128 + i * 64 + rowin;
      async16(mat + gbase + (size_t)r * 4096 + kt * 64 + cslot * 8, ldst + i * 8192);
    }
  };

  // prologue: tiles 0 and 1 fully staged (8 + 8 loads); tile 0 landed
#pragma unroll
  for (int c = 0; c < 4; ++c) stage(0, c);
#pragma unroll
  for (int c = 0; c < 4; ++c) stage(1, c);
  asm volatile("s_waitcnt vmcnt(8)" ::: "memory");
  BARRIER();

  for (int tt = 0; tt < 62; tt += 2) {
    TILE_BODY(tt, 0, 0);
    TILE_BODY(tt + 1, 1, 0);
  }
  TILE_BODY(62, 0, 1);
  TILE_BODY(63, 1, 2);

#undef TILE_BODY
#undef MFQ

  // C/D layout (m89-verified): col = lane&15, row = (lane>>4)*4 + reg
  int r0 = (l >> 4) * 4;
#pragma unroll
  for (int mi = 0; mi < 8; ++mi) {
    size_t row = (size_t)(bm * 256 + wm + mi * 16 + r0);
#pragma unroll
    for (int ni = 0; ni < 4; ++ni) {
      int col = bn * 256 + wn + ni * 16 + (l & 15);
#pragma unroll
      for (int r = 0; r < 4; ++r)
        C[(row + r) * 4096 + col] = acc[mi][ni][r];
    }
  }
}

// ---------------- fallback (no workspace): fp32 register-blocked ----------------
__global__ __launch_bounds__(256) void fallback_kern(const float* __restrict__ x,
                                                     const float* __restrict__ W,
                                                     float* __restrict__ out) {
  int bi = blockIdx.x & 63;
  int bb = blockIdx.x >> 6;
  int t = threadIdx.x;
  int m = t & 63;
  int cg = t >> 6;
  __shared__ float xs[64][65];
  __shared__ float ws[64];
  float acc[16];
#pragma unroll
  for (int e = 0; e < 16; ++e) acc[e] = 0.f;
  for (int j = 0; j < 64; ++j) {
    __syncthreads();
#pragma unroll
    for (int r = 0; r < 16; ++r) {
      int idx = t + 256 * r;
      int rr = idx >> 6, cc = idx & 63;
      xs[rr][cc] = x[(size_t)(bb * 64 + rr) * 4096 + j * 64 + cc];
    }
    if (t < 64) ws[t] = W[((size_t)(bi * 64 + j)) * 64 + t];
    __syncthreads();
    float xr[64];
#pragma unroll
    for (int e = 0; e < 64; ++e) xr[e] = xs[m][(cg * 16 + e) & 63];
#pragma unroll
    for (int mm = 0; mm < 64; ++mm) {
      float wv = ws[mm];
#pragma unroll
      for (int cc2 = 0; cc2 < 16; ++cc2)
        acc[cc2] = __builtin_fmaf(xr[(cc2 - mm) & 63], wv, acc[cc2]);
    }
  }
  float* dst = out + (size_t)(bb * 64 + m) * 4096 + bi * 64 + cg * 16;
#pragma unroll
  for (int cc2 = 0; cc2 < 16; ++cc2) dst[cc2] = acc[cc2];
}

extern "C" void kernel_launch(void* const* d_in, const int* in_sizes, int n_in,
                              void* d_out, int out_size, void* d_ws, size_t ws_size,
                              hipStream_t stream) {
  const float* x = (const float*)d_in[0];
  const float* W = (const float*)d_in[1];
  float* out = (float*)d_out;
  const size_t need = (size_t)2 * 4096 * 4096 * sizeof(unsigned short);  // 64 MB
  if (ws_size >= need) {
    unsigned short* xb = (unsigned short*)d_ws;
    unsigned short* Mb = xb + (size_t)4096 * 4096;
    prep_kern<<<dim3(9216), dim3(256), 0, stream>>>(x, W, xb, Mb);
    gemm8<<<dim3(256), dim3(512), 0, stream>>>(xb, Mb, out);
  } else {
    fallback_kern<<<dim3(4096), dim3(256), 0, stream>>>(x, W, out);
  }
}